// Round 5
// baseline (773.492 us; speedup 1.0000x reference)
//
#include <hip/hip_runtime.h>

constexpr int IND = 128;
constexpr int HD  = 96;
constexpr int OD  = 64;
constexpr int NL  = 4;

struct F3 { float x, y, z; };

__global__ __launch_bounds__(256) void k_hist(const int* __restrict__ dst, int* __restrict__ deg, int E) {
    int e = blockIdx.x * 256 + threadIdx.x;
    if (e < E) atomicAdd(&deg[dst[e]], 1);
}

__global__ __launch_bounds__(256) void k_scan1(const int* __restrict__ deg, int* __restrict__ bsum, int n) {
    int tid = threadIdx.x;
    int base = blockIdx.x * 1024 + tid * 4;
    int s = 0;
    #pragma unroll
    for (int q = 0; q < 4; ++q) { int i = base + q; if (i < n) s += deg[i]; }
    #pragma unroll
    for (int o = 32; o > 0; o >>= 1) s += __shfl_xor(s, o);
    __shared__ int wsum[4];
    int lane = tid & 63, wid = tid >> 6;
    if (lane == 0) wsum[wid] = s;
    __syncthreads();
    if (tid == 0) bsum[blockIdx.x] = wsum[0] + wsum[1] + wsum[2] + wsum[3];
}

__global__ void k_scan2(const int* __restrict__ bsum, int* __restrict__ boff, int nb,
                        int* __restrict__ row_ptr, int n, int E) {
    int l = threadIdx.x;
    int v = (l < nb) ? bsum[l] : 0;
    int incl = v;
    #pragma unroll
    for (int o = 1; o < 64; o <<= 1) { int t = __shfl_up(incl, o); if (l >= o) incl += t; }
    if (l < nb) boff[l] = incl - v;
    if (l == 0) row_ptr[n] = E;
}

__global__ __launch_bounds__(256) void k_scan3(const int* __restrict__ deg, const int* __restrict__ boff,
                                               int* __restrict__ row_ptr, int n) {
    int tid = threadIdx.x;
    int base = blockIdx.x * 1024 + tid * 4;
    int d[4];
    #pragma unroll
    for (int q = 0; q < 4; ++q) { int i = base + q; d[q] = (i < n) ? deg[i] : 0; }
    int tsum = d[0] + d[1] + d[2] + d[3];
    int incl = tsum;
    #pragma unroll
    for (int o = 1; o < 64; o <<= 1) { int t = __shfl_up(incl, o); if ((tid & 63) >= o) incl += t; }
    __shared__ int wsum[4];
    int lane = tid & 63, wid = tid >> 6;
    if (lane == 63) wsum[wid] = incl;
    __syncthreads();
    int woff = 0;
    for (int w = 0; w < wid; ++w) woff += wsum[w];
    int run = boff[blockIdx.x] + woff + (incl - tsum);
    #pragma unroll
    for (int q = 0; q < 4; ++q) {
        int i = base + q;
        if (i < n) { row_ptr[i] = run; run += d[q]; }
    }
}

// fill CSR: single 8B scatter per edge: sep[slot] = (src[e], e).
// (round-4's per-layer ew scatter caused 150MB of RMW write traffic — ew is now
//  permuted by GATHER in k_perm instead.)
__global__ __launch_bounds__(256) void k_fill(const int* __restrict__ src, const int* __restrict__ dst,
                                              const int* __restrict__ row_ptr, int* __restrict__ cursor,
                                              int2* __restrict__ sep, int E) {
    int e = blockIdx.x * 256 + threadIdx.x;
    if (e >= E) return;
    int d = dst[e];
    int pos = atomicAdd(&cursor[d], 1);
    sep[row_ptr[d] + pos] = make_int2(src[e], e);
}

// slot-ordered edge weights via gather (sequential writes, random reads — no RMW amp):
// ewp[l][slot] = (convE[2l][e], convE[2l+1][e])
__global__ __launch_bounds__(256) void k_perm(const int2* __restrict__ sep,
                                              const float* __restrict__ convE,
                                              float2* __restrict__ ewp, int E) {
    int i = blockIdx.x * 256 + threadIdx.x;
    if (i >= E) return;
    int e = sep[i].y;
    #pragma unroll
    for (int l = 0; l < NL; ++l) {
        float2 w;
        w.x = convE[(size_t)(2 * l)     * E + e];
        w.y = convE[(size_t)(2 * l + 1) * E + e];
        ewp[(size_t)l * E + i] = w;
    }
}

// Fused layer: agg (gather into LDS) + dual-head GEMM + relu.
// BR=16 nodes/block, 256 threads, LDS 12.3KB -> hits the 32-wave/CU cap
// (8 blocks x 4 waves; LDS 98KB/CU, VGPR<=64). Round-4's BR=32 (24.6KB) only
// reached 35% occupancy and the latency-bound gather ran at 1.3TB/s.
// NOTE: hin and hout MUST be distinct buffers (gather reads arbitrary rows
// cross-block; in-place update races — caused round-2 failure).
constexpr int BR = 16;

__global__ __launch_bounds__(256) void k_layer(const float* __restrict__ hin,
                                               const int* __restrict__ row_ptr,
                                               const int2* __restrict__ sep,
                                               const float2* __restrict__ ewp,
                                               const float* __restrict__ W,   // [2][96][96]
                                               float* __restrict__ hout, int n) {
    __shared__ float sA0[BR][HD];   // phase-1 writes stride-3 (gcd(3,32)=1, bijective);
    __shared__ float sA1[BR][HD];   // phase-2 reads are half-wave broadcasts -> free
    int tid = threadIdx.x;
    int brow = blockIdx.x * BR;

    // ---- phase 1: aggregate this block's 16 rows into LDS (2 rows per 32-lane group) ----
    {
        int grp = tid >> 5;          // 0..7
        int lane = tid & 31;
        int off = lane * 3;          // 3 floats per lane
        for (int q = 0; q < 2; ++q) {
            int r = grp * 2 + q;
            int g = brow + r;
            float a0x = 0.f, a0y = 0.f, a0z = 0.f;
            float a1x = 0.f, a1y = 0.f, a1z = 0.f;
            if (g < n) {
                int i = row_ptr[g], end = row_ptr[g + 1];
                for (; i + 2 <= end; i += 2) {
                    int s0 = sep[i].x;
                    int s1 = sep[i + 1].x;
                    float2 w0 = ewp[i];
                    float2 w1 = ewp[i + 1];
                    F3 v0 = *(const F3*)(hin + (size_t)s0 * HD + off);
                    F3 v1 = *(const F3*)(hin + (size_t)s1 * HD + off);
                    a0x = fmaf(w0.x, v0.x, a0x); a0y = fmaf(w0.x, v0.y, a0y); a0z = fmaf(w0.x, v0.z, a0z);
                    a1x = fmaf(w0.y, v0.x, a1x); a1y = fmaf(w0.y, v0.y, a1y); a1z = fmaf(w0.y, v0.z, a1z);
                    a0x = fmaf(w1.x, v1.x, a0x); a0y = fmaf(w1.x, v1.y, a0y); a0z = fmaf(w1.x, v1.z, a0z);
                    a1x = fmaf(w1.y, v1.x, a1x); a1y = fmaf(w1.y, v1.y, a1y); a1z = fmaf(w1.y, v1.z, a1z);
                }
                if (i < end) {
                    int s0 = sep[i].x;
                    float2 w0 = ewp[i];
                    F3 v0 = *(const F3*)(hin + (size_t)s0 * HD + off);
                    a0x = fmaf(w0.x, v0.x, a0x); a0y = fmaf(w0.x, v0.y, a0y); a0z = fmaf(w0.x, v0.z, a0z);
                    a1x = fmaf(w0.y, v0.x, a1x); a1y = fmaf(w0.y, v0.y, a1y); a1z = fmaf(w0.y, v0.z, a1z);
                }
            }
            sA0[r][off] = a0x; sA0[r][off + 1] = a0y; sA0[r][off + 2] = a0z;
            sA1[r][off] = a1x; sA1[r][off + 1] = a1y; sA1[r][off + 2] = a1z;
        }
    }
    __syncthreads();

    // ---- phase 2: h = relu(A0@W0 + A1@W1), W from global (L2-hot) ----
    int tx = tid & 31;               // cols 3tx..3tx+2
    int ty = tid >> 5;               // rows 2ty..2ty+1
    float acc[2][3];
    #pragma unroll
    for (int r = 0; r < 2; ++r) { acc[r][0] = 0.f; acc[r][1] = 0.f; acc[r][2] = 0.f; }

    #pragma unroll
    for (int head = 0; head < 2; ++head) {
        const float* Wh = W + (size_t)head * HD * HD;
        const float (*sAh)[HD] = head ? sA1 : sA0;
        #pragma unroll 4
        for (int kk = 0; kk < HD; ++kk) {
            F3 wv = *(const F3*)(Wh + (size_t)kk * HD + 3 * tx);
            float a[2];
            #pragma unroll
            for (int r = 0; r < 2; ++r) a[r] = sAh[2 * ty + r][kk];
            #pragma unroll
            for (int r = 0; r < 2; ++r) {
                acc[r][0] = fmaf(a[r], wv.x, acc[r][0]);
                acc[r][1] = fmaf(a[r], wv.y, acc[r][1]);
                acc[r][2] = fmaf(a[r], wv.z, acc[r][2]);
            }
        }
    }
    #pragma unroll
    for (int r = 0; r < 2; ++r) {
        int gr = brow + 2 * ty + r;
        if (gr < n) {
            float* op = hout + (size_t)gr * HD + 3 * tx;
            op[0] = fmaxf(acc[r][0], 0.f);
            op[1] = fmaxf(acc[r][1], 0.f);
            op[2] = fmaxf(acc[r][2], 0.f);
        }
    }
}

// Encoder/decoder GEMM: 64 rows/block, 256 threads, full-K A staged in LDS, W from global.
template<int K, int NO, bool RELU>
__global__ __launch_bounds__(256) void k_mlp(const float* __restrict__ A,
                                             const float* __restrict__ W,
                                             const float* __restrict__ bias,
                                             float* __restrict__ out, int n) {
    constexpr int P = K + 4;
    constexpr int NC = NO / 32;
    __shared__ float sA[64][P];
    int tid = threadIdx.x;
    int brow = blockIdx.x * 64;
    constexpr int F4 = K / 4;
    for (int i = tid; i < 64 * F4; i += 256) {
        int r = i / F4, c4 = i % F4;
        int gr = brow + r;
        float4 v = make_float4(0.f, 0.f, 0.f, 0.f);
        if (gr < n) v = *(const float4*)(A + (size_t)gr * K + 4 * c4);
        *(float4*)&sA[r][4 * c4] = v;
    }
    __syncthreads();
    int tx = tid & 31;
    int ty = tid >> 5;
    float acc[8][NC];
    #pragma unroll
    for (int r = 0; r < 8; ++r)
        #pragma unroll
        for (int j = 0; j < NC; ++j) acc[r][j] = 0.f;
    #pragma unroll 4
    for (int kk = 0; kk < K; ++kk) {
        float wv[NC];
        #pragma unroll
        for (int j = 0; j < NC; ++j) wv[j] = W[(size_t)kk * NO + NC * tx + j];
        float a[8];
        #pragma unroll
        for (int r = 0; r < 8; ++r) a[r] = sA[8 * ty + r][kk];
        #pragma unroll
        for (int r = 0; r < 8; ++r)
            #pragma unroll
            for (int j = 0; j < NC; ++j) acc[r][j] = fmaf(a[r], wv[j], acc[r][j]);
    }
    #pragma unroll
    for (int r = 0; r < 8; ++r) {
        int gr = brow + 8 * ty + r;
        if (gr < n) {
            float* op = out + (size_t)gr * NO + NC * tx;
            #pragma unroll
            for (int j = 0; j < NC; ++j) {
                float v = acc[r][j] + bias[NC * tx + j];
                if (RELU) v = fmaxf(v, 0.f);
                op[j] = v;
            }
        }
    }
}

extern "C" void kernel_launch(void* const* d_in, const int* in_sizes, int n_in,
                              void* d_out, int out_size, void* d_ws, size_t ws_size,
                              hipStream_t stream) {
    const float* x     = (const float*)d_in[0];
    const int*   ei    = (const int*)  d_in[1];
    const float* enc_w = (const float*)d_in[2];
    const float* enc_b = (const float*)d_in[3];
    const float* dec_w = (const float*)d_in[4];
    const float* dec_b = (const float*)d_in[5];
    const float* convW = (const float*)d_in[6];
    const float* convE = (const float*)d_in[7];

    const int N = in_sizes[0] / IND;
    const int E = in_sizes[1] / 2;
    const int* src = ei;
    const int* dst = ei + E;
    float* fout = (float*)d_out;

    char* wp = (char*)d_ws;
    auto carve = [&](size_t bytes) -> void* {
        void* p = (void*)wp;
        wp += (bytes + 255) & ~(size_t)255;
        return p;
    };
    int*    deg     = (int*)carve(2 * (size_t)N * 4);   // deg | cursor (one memset)
    int*    cursor  = deg + N;
    int*    row_ptr = (int*)carve(((size_t)N + 1) * 4);
    int*    bsum    = (int*)carve(64 * 4);
    int*    boff    = (int*)carve(64 * 4);
    int2*   sep     = (int2*)carve((size_t)E * 8);
    float2* ewp     = (float2*)carve((size_t)NL * E * 8);
    float*  hbuf    = (float*)carve((size_t)N * HD * 4);

    hipMemsetAsync(deg, 0, 2 * (size_t)N * 4, stream);

    int ebl = (E + 255) / 256;
    int nb  = (N + 1023) / 1024;
    k_hist<<<ebl, 256, 0, stream>>>(dst, deg, E);
    k_scan1<<<nb, 256, 0, stream>>>(deg, bsum, N);
    k_scan2<<<1, 64, 0, stream>>>(bsum, boff, nb, row_ptr, N, E);
    k_scan3<<<nb, 256, 0, stream>>>(deg, boff, row_ptr, N);
    k_fill<<<ebl, 256, 0, stream>>>(src, dst, row_ptr, cursor, sep, E);
    k_perm<<<ebl, 256, 0, stream>>>(sep, convE, ewp, E);

    int gbl64 = (N + 63) / 64;
    int gblBR = (N + BR - 1) / BR;
    float* hfin = fout + (size_t)N * OD;   // output-1 region doubles as h ping-pong slot

    // ping-pong: enc->hfin; L0: hfin->hbuf; L1: hbuf->hfin; L2: hfin->hbuf; L3: hbuf->hfin
    k_mlp<IND, HD, true><<<gbl64, 256, 0, stream>>>(x, enc_w, enc_b, hfin, N);

    float* bufs[2] = { hfin, hbuf };
    for (int l = 0; l < NL; ++l) {
        const float* Wl = convW + (size_t)l * 2 * HD * HD;
        const float* hi = bufs[l & 1];
        float*       ho = bufs[(l + 1) & 1];
        k_layer<<<gblBR, 256, 0, stream>>>(hi, row_ptr, sep, ewp + (size_t)l * E, Wl, ho, N);
    }
    // NL even -> final h is in hfin (= fout + N*OD), exactly output 1.
    k_mlp<HD, OD, false><<<gbl64, 256, 0, stream>>>(hfin, dec_w, dec_b, fout, N);
}

// Round 6
// 686.418 us; speedup vs baseline: 1.1269x; 1.1269x over previous
//
#include <hip/hip_runtime.h>

constexpr int IND = 128;
constexpr int HD  = 96;
constexpr int OD  = 64;
constexpr int NL  = 4;

struct F3 { float x, y, z; };

__global__ __launch_bounds__(256) void k_hist(const int* __restrict__ dst, int* __restrict__ deg, int E) {
    int e = blockIdx.x * 256 + threadIdx.x;
    if (e < E) atomicAdd(&deg[dst[e]], 1);
}

__global__ __launch_bounds__(256) void k_scan1(const int* __restrict__ deg, int* __restrict__ bsum, int n) {
    int tid = threadIdx.x;
    int base = blockIdx.x * 1024 + tid * 4;
    int s = 0;
    #pragma unroll
    for (int q = 0; q < 4; ++q) { int i = base + q; if (i < n) s += deg[i]; }
    #pragma unroll
    for (int o = 32; o > 0; o >>= 1) s += __shfl_xor(s, o);
    __shared__ int wsum[4];
    int lane = tid & 63, wid = tid >> 6;
    if (lane == 0) wsum[wid] = s;
    __syncthreads();
    if (tid == 0) bsum[blockIdx.x] = wsum[0] + wsum[1] + wsum[2] + wsum[3];
}

__global__ void k_scan2(const int* __restrict__ bsum, int* __restrict__ boff, int nb,
                        int* __restrict__ row_ptr, int n, int E) {
    int l = threadIdx.x;
    int v = (l < nb) ? bsum[l] : 0;
    int incl = v;
    #pragma unroll
    for (int o = 1; o < 64; o <<= 1) { int t = __shfl_up(incl, o); if (l >= o) incl += t; }
    if (l < nb) boff[l] = incl - v;
    if (l == 0) row_ptr[n] = E;
}

__global__ __launch_bounds__(256) void k_scan3(const int* __restrict__ deg, const int* __restrict__ boff,
                                               int* __restrict__ row_ptr, int n) {
    int tid = threadIdx.x;
    int base = blockIdx.x * 1024 + tid * 4;
    int d[4];
    #pragma unroll
    for (int q = 0; q < 4; ++q) { int i = base + q; d[q] = (i < n) ? deg[i] : 0; }
    int tsum = d[0] + d[1] + d[2] + d[3];
    int incl = tsum;
    #pragma unroll
    for (int o = 1; o < 64; o <<= 1) { int t = __shfl_up(incl, o); if ((tid & 63) >= o) incl += t; }
    __shared__ int wsum[4];
    int lane = tid & 63, wid = tid >> 6;
    if (lane == 63) wsum[wid] = incl;
    __syncthreads();
    int woff = 0;
    for (int w = 0; w < wid; ++w) woff += wsum[w];
    int run = boff[blockIdx.x] + woff + (incl - tsum);
    #pragma unroll
    for (int q = 0; q < 4; ++q) {
        int i = base + q;
        if (i < n) { row_ptr[i] = run; run += d[q]; }
    }
}

// fill CSR: single 8B scatter per edge: sep[slot] = (src[e], e).
__global__ __launch_bounds__(256) void k_fill(const int* __restrict__ src, const int* __restrict__ dst,
                                              const int* __restrict__ row_ptr, int* __restrict__ cursor,
                                              int2* __restrict__ sep, int E) {
    int e = blockIdx.x * 256 + threadIdx.x;
    if (e >= E) return;
    int d = dst[e];
    int pos = atomicAdd(&cursor[d], 1);
    sep[row_ptr[d] + pos] = make_int2(src[e], e);
}

// per-layer slot-ordered edge weights (gather reads, sequential writes):
// ewq[i] = (c0[sep[i].y], c1[sep[i].y])
__global__ __launch_bounds__(256) void k_perm(const int2* __restrict__ sep,
                                              const float* __restrict__ c0,
                                              const float* __restrict__ c1,
                                              float2* __restrict__ ewq, int E) {
    int i = blockIdx.x * 256 + threadIdx.x;
    if (i >= E) return;
    int e = sep[i].y;
    ewq[i] = make_float2(c0[e], c1[e]);
}

// A0[v,:] = sum_e ew0*h[src], A1 likewise. 8 nodes/block, one 32-lane group per
// node, 3 floats/lane, no LDS / no barrier (block-level imbalance averages out
// across 6250 blocks). Unroll-4 keeps 4 row-gathers in flight per group.
__global__ __launch_bounds__(256) void k_agg(const float* __restrict__ h, const int* __restrict__ row_ptr,
                                             const int2* __restrict__ sep, const float2* __restrict__ ewq,
                                             float* __restrict__ A0, float* __restrict__ A1, int n) {
    int g = blockIdx.x * 8 + (threadIdx.x >> 5);
    int lane = threadIdx.x & 31;
    if (g >= n) return;
    int beg = row_ptr[g], end = row_ptr[g + 1];
    float a0x = 0.f, a0y = 0.f, a0z = 0.f;
    float a1x = 0.f, a1y = 0.f, a1z = 0.f;
    int off = lane * 3;
    int i = beg;
    for (; i + 4 <= end; i += 4) {
        int2 s0 = sep[i], s1 = sep[i + 1], s2 = sep[i + 2], s3 = sep[i + 3];
        float2 w0 = ewq[i], w1 = ewq[i + 1], w2 = ewq[i + 2], w3 = ewq[i + 3];
        F3 v0 = *(const F3*)(h + (size_t)s0.x * HD + off);
        F3 v1 = *(const F3*)(h + (size_t)s1.x * HD + off);
        F3 v2 = *(const F3*)(h + (size_t)s2.x * HD + off);
        F3 v3 = *(const F3*)(h + (size_t)s3.x * HD + off);
        a0x = fmaf(w0.x, v0.x, a0x); a0y = fmaf(w0.x, v0.y, a0y); a0z = fmaf(w0.x, v0.z, a0z);
        a1x = fmaf(w0.y, v0.x, a1x); a1y = fmaf(w0.y, v0.y, a1y); a1z = fmaf(w0.y, v0.z, a1z);
        a0x = fmaf(w1.x, v1.x, a0x); a0y = fmaf(w1.x, v1.y, a0y); a0z = fmaf(w1.x, v1.z, a0z);
        a1x = fmaf(w1.y, v1.x, a1x); a1y = fmaf(w1.y, v1.y, a1y); a1z = fmaf(w1.y, v1.z, a1z);
        a0x = fmaf(w2.x, v2.x, a0x); a0y = fmaf(w2.x, v2.y, a0y); a0z = fmaf(w2.x, v2.z, a0z);
        a1x = fmaf(w2.y, v2.x, a1x); a1y = fmaf(w2.y, v2.y, a1y); a1z = fmaf(w2.y, v2.z, a1z);
        a0x = fmaf(w3.x, v3.x, a0x); a0y = fmaf(w3.x, v3.y, a0y); a0z = fmaf(w3.x, v3.z, a0z);
        a1x = fmaf(w3.y, v3.x, a1x); a1y = fmaf(w3.y, v3.y, a1y); a1z = fmaf(w3.y, v3.z, a1z);
    }
    for (; i < end; ++i) {
        int2 s0 = sep[i];
        float2 w0 = ewq[i];
        F3 v0 = *(const F3*)(h + (size_t)s0.x * HD + off);
        a0x = fmaf(w0.x, v0.x, a0x); a0y = fmaf(w0.x, v0.y, a0y); a0z = fmaf(w0.x, v0.z, a0z);
        a1x = fmaf(w0.y, v0.x, a1x); a1y = fmaf(w0.y, v0.y, a1y); a1z = fmaf(w0.y, v0.z, a1z);
    }
    float* p0 = A0 + (size_t)g * HD + off;
    p0[0] = a0x; p0[1] = a0y; p0[2] = a0z;
    float* p1 = A1 + (size_t)g * HD + off;
    p1[0] = a1x; p1[1] = a1y; p1[2] = a1z;
}

// GEMM: out = [relu]( A0@W0 [+ A1@W1] [+ bias] ).  64 rows/block, 256 threads,
// FULL-K staging of A in LDS (so out may alias A0: each block stages all its
// rows before writing, blocks own disjoint rows, stream serializes kernels).
// W from global: per-block traffic 590KB, 782 blocks -> ~460MB L2/layer (~13µs).
template<int K, int NO, bool DUAL, bool RELU, bool BIAS>
__global__ __launch_bounds__(256) void k_gemm(const float* __restrict__ A0p, const float* __restrict__ A1p,
                                              const float* __restrict__ W0p,
                                              const float* __restrict__ bias,
                                              float* __restrict__ out, int n) {
    constexpr int NC = NO / 32;
    constexpr int F4 = K / 4;
    __shared__ float sA0[64][K];
    __shared__ float sA1[DUAL ? 64 : 1][DUAL ? K : 1];
    int tid = threadIdx.x;
    int brow = blockIdx.x * 64;

    for (int j = tid; j < 64 * F4; j += 256) {
        int r = j / F4, c4 = j % F4;
        int gr = brow + r;
        float4 v = make_float4(0.f, 0.f, 0.f, 0.f);
        if (gr < n) v = *(const float4*)(A0p + (size_t)gr * K + 4 * c4);
        *(float4*)&sA0[r][4 * c4] = v;
        if (DUAL) {
            float4 u = make_float4(0.f, 0.f, 0.f, 0.f);
            if (gr < n) u = *(const float4*)(A1p + (size_t)gr * K + 4 * c4);
            *(float4*)&sA1[r][4 * c4] = u;
        }
    }
    __syncthreads();

    int tx = tid & 31;               // cols NC*tx .. NC*tx+NC-1
    int ty = tid >> 5;               // rows 8ty .. 8ty+7
    float acc[8][NC];
    #pragma unroll
    for (int r = 0; r < 8; ++r)
        #pragma unroll
        for (int j = 0; j < NC; ++j) acc[r][j] = 0.f;

    #pragma unroll
    for (int head = 0; head < (DUAL ? 2 : 1); ++head) {
        const float* Wh = W0p + (size_t)head * K * NO;
        #pragma unroll 1
        for (int kb = 0; kb < K; kb += 4) {
            float4 a4[8];
            #pragma unroll
            for (int r = 0; r < 8; ++r)
                a4[r] = head ? *(const float4*)&sA1[8 * ty + r][kb]
                             : *(const float4*)&sA0[8 * ty + r][kb];
            #pragma unroll
            for (int q = 0; q < 4; ++q) {
                float wv[NC];
                #pragma unroll
                for (int j = 0; j < NC; ++j) wv[j] = Wh[(size_t)(kb + q) * NO + NC * tx + j];
                #pragma unroll
                for (int r = 0; r < 8; ++r) {
                    const float* ap = (const float*)&a4[r];
                    float av = ap[q];
                    #pragma unroll
                    for (int j = 0; j < NC; ++j) acc[r][j] = fmaf(av, wv[j], acc[r][j]);
                }
            }
        }
    }
    #pragma unroll
    for (int r = 0; r < 8; ++r) {
        int gr = brow + 8 * ty + r;
        if (gr < n) {
            float* op = out + (size_t)gr * NO + NC * tx;
            #pragma unroll
            for (int j = 0; j < NC; ++j) {
                float v = acc[r][j];
                if (BIAS) v += bias[NC * tx + j];
                if (RELU) v = fmaxf(v, 0.f);
                op[j] = v;
            }
        }
    }
}

extern "C" void kernel_launch(void* const* d_in, const int* in_sizes, int n_in,
                              void* d_out, int out_size, void* d_ws, size_t ws_size,
                              hipStream_t stream) {
    const float* x     = (const float*)d_in[0];
    const int*   ei    = (const int*)  d_in[1];
    const float* enc_w = (const float*)d_in[2];
    const float* enc_b = (const float*)d_in[3];
    const float* dec_w = (const float*)d_in[4];
    const float* dec_b = (const float*)d_in[5];
    const float* convW = (const float*)d_in[6];
    const float* convE = (const float*)d_in[7];

    const int N = in_sizes[0] / IND;
    const int E = in_sizes[1] / 2;
    const int* src = ei;
    const int* dst = ei + E;
    float* fout = (float*)d_out;

    char* wp = (char*)d_ws;
    auto carve = [&](size_t bytes) -> void* {
        void* p = (void*)wp;
        wp += (bytes + 255) & ~(size_t)255;
        return p;
    };
    int*    deg     = (int*)carve(2 * (size_t)N * 4);   // deg | cursor (one memset)
    int*    cursor  = deg + N;
    int*    row_ptr = (int*)carve(((size_t)N + 1) * 4);
    int*    bsum    = (int*)carve(64 * 4);
    int*    boff    = (int*)carve(64 * 4);
    int2*   sep     = (int2*)carve((size_t)E * 8);
    float*  P0      = (float*)carve((size_t)N * HD * 4);
    float*  P1      = (float*)carve((size_t)N * HD * 4);
    float*  P2      = (float*)carve((size_t)N * HD * 4);
    // total ws: ~64.7MB (== round-1's proven footprint)

    // per-layer edge weights live in the out0 region (12.8MB; decoder writes it last)
    float2* ewq = (float2*)fout;

    hipMemsetAsync(deg, 0, 2 * (size_t)N * 4, stream);

    int ebl = (E + 255) / 256;
    int nb  = (N + 1023) / 1024;
    k_hist<<<ebl, 256, 0, stream>>>(dst, deg, E);
    k_scan1<<<nb, 256, 0, stream>>>(deg, bsum, N);
    k_scan2<<<1, 64, 0, stream>>>(bsum, boff, nb, row_ptr, N, E);
    k_scan3<<<nb, 256, 0, stream>>>(deg, boff, row_ptr, N);
    k_fill<<<ebl, 256, 0, stream>>>(src, dst, row_ptr, cursor, sep, E);

    int gbl64 = (N + 63) / 64;
    int gbl8  = (N + 7) / 8;
    float* hfin = fout + (size_t)N * OD;   // out1 region: final h lands here

    // encoder: P0 = relu(x @ enc_w + enc_b)
    k_gemm<IND, HD, false, true, true><<<gbl64, 256, 0, stream>>>(x, nullptr, enc_w, enc_b, P0, N);

    // schedule: L0 P0->(P1,P2)->P1 ; L1 P1->(P0,P2)->P0 ; L2 P0->(P1,P2)->P1 ;
    //           L3 P1->(P0,P2)->hfin   (dual-gemm writes in-place over its A0)
    float* hin[NL]  = { P0, P1, P0, P1 };
    float* ha0[NL]  = { P1, P0, P1, P0 };
    float* hout[NL] = { P1, P0, P1, hfin };
    for (int l = 0; l < NL; ++l) {
        const float* c0 = convE + (size_t)(2 * l)     * E;
        const float* c1 = convE + (size_t)(2 * l + 1) * E;
        const float* Wl = convW + (size_t)l * 2 * HD * HD;
        k_perm<<<ebl, 256, 0, stream>>>(sep, c0, c1, ewq, E);
        k_agg<<<gbl8, 256, 0, stream>>>(hin[l], row_ptr, sep, ewq, ha0[l], P2, N);
        k_gemm<HD, HD, true, true, false><<<gbl64, 256, 0, stream>>>(ha0[l], P2, Wl, nullptr, hout[l], N);
    }
    // decoder: out0 = hfin @ dec_w + dec_b  (overwrites the ewq scratch region)
    k_gemm<HD, OD, false, false, true><<<gbl64, 256, 0, stream>>>(hfin, nullptr, dec_w, dec_b, fout, N);
}